// Round 7
// baseline (142.534 us; speedup 1.0000x reference)
//
#include <hip/hip_runtime.h>
#include <cstdint>

typedef __attribute__((ext_vector_type(8))) short bf16x8;    // 8 bf16 = 4 VGPRs
typedef __attribute__((ext_vector_type(16))) float f32x16;   // 32x32 MFMA C/D
typedef __attribute__((ext_vector_type(4))) float f4;
typedef __attribute__((ext_vector_type(8))) unsigned short u16x8;
typedef unsigned short u16;

// JOURNAL:
// R9: 32x32x16 MFMA beats 16x16x32 (-5us). R11/R12: ws aliasing abort -> fixed.
// R13 FAILED: 128^2 tile alone: 47.2us gemm12 (Occ 12%, MfmaUtil 15%).
// R14 PARTIAL: 2-phase dbuf + counted vmcnt(8): 147->139.7. GEMMs ~41us each.
// R16: XCD supertile swizzle: ~noise. ACCOUNTING: kernels ~95us; ~42us fixed
//      harness ws re-poison (fillBuffer) inside timed window.
// R17 FAILED: gemm3 m97-parity single-buf: 148.2 (syncthreads-drain serializes;
//      same-phase blocks don't skew at 8 iters).
// R18 NEUTRAL: gemm3 256^2 2-phase (1 blk/CU): gemm3 still ~38-40us. ALL
//      2-phase variants pin at ~450-500 TF regardless of tile. Matches m233
//      (2ph = 607 TF, 72% critical path = stage+vmcnt+barrier) + m218
//      (counted vmcnt only pays with >1 tile in flight) + regime-gate
//      (8-phase is the prerequisite, tile gates nothing).
// R19 (this round): gemm3 -> deep-pipeline schedule (T3+T4+T5): ring of
//      4 x BK=32 buffers (128KB), prefetch depth 3, vmcnt(8) steady
//      (epilogue 8->4->0, never 0 in main loop), per-tile 2 phases
//      {6 ds_read | stage 1 unit | barrier | lgkm0 | sched_barrier |
//      setprio1 | 8 MFMA | setprio0 | barrier}. New BK=32 bank-balanced
//      swizzle gc = pc ^ ((row>>1)&3) (both-sides, rule #21; uniform over
//      8 bank-groups). Grid/decode/epilogue/reduce4 unchanged from R18.
//      Predict gemm3 38->13-18us, total ->112-120. Fail=race; neutral=
//      per-CU staging-BW floor -> attack traffic next; win -> port gemm12.

__device__ __forceinline__ u16 f2bf(float f) {
  uint32_t u = __builtin_bit_cast(uint32_t, f);
  u += 0x7fffu + ((u >> 16) & 1u);          // round-to-nearest-even
  return (u16)(u >> 16);
}

__device__ __forceinline__ float bf2f(u16 h) {
  return __builtin_bit_cast(float, (uint32_t)h << 16);
}

__device__ __forceinline__ void async_cp16(const void* g, void* l) {
  __builtin_amdgcn_global_load_lds(
      (const __attribute__((address_space(1))) uint32_t*)g,
      (__attribute__((address_space(3))) uint32_t*)l, 16, 0, 0);
}

// cast x | features | prototypes -> contiguous bf16 region in ws (8 elem/thread)
__global__ __launch_bounds__(256) void cast3(
    const float* __restrict__ x, const float* __restrict__ f,
    const float* __restrict__ p, u16* __restrict__ dst,
    int n1, int n2, int n3) {
  int i = (blockIdx.x * 256 + threadIdx.x) * 8;
  const float* src;
  int local;
  if (i < n1) { src = x; local = i; }
  else if (i < n1 + n2) { src = f; local = i - n1; }
  else if (i < n1 + n2 + n3) { src = p; local = i - n1 - n2; }
  else return;
  f4 a = *(const f4*)(src + local);
  f4 b = *(const f4*)(src + local + 4);
  u16x8 o;
  o[0] = f2bf(a.x); o[1] = f2bf(a.y); o[2] = f2bf(a.z); o[3] = f2bf(a.w);
  o[4] = f2bf(b.x); o[5] = f2bf(b.y); o[6] = f2bf(b.z); o[7] = f2bf(b.w);
  *(u16x8*)(dst + i) = o;
}

// ================= 128^2 2-phase mainloop (gemm12, proven R14/R16) ==========
// C += A @ B^T with 32x32x16 MFMA. 16B-chunk XOR swizzle (0 bank conflicts).
// Wave grid 2x2 (256 thr): wave covers 64x64 = 2x2 acc tiles of 32x32.

__device__ __forceinline__ void stage_tile(
    const u16* __restrict__ A, const u16* __restrict__ B, int K,
    int k0, int tid, u16* L) {
  constexpr int TM = 128, TN = 128;
  const int wave = tid >> 6;
  #pragma unroll
  for (int it = 0; it < TM / 32; ++it) {
    int c = it * 256 + tid;            // chunk index = LDS position
    int row = c >> 3, pc = c & 7;
    int gc = pc ^ (row & 7);           // which global 16B chunk lands here
    async_cp16(A + (size_t)row * K + (k0 + gc * 8),
               &L[(it * 256 + wave * 64) * 8]);
  }
  #pragma unroll
  for (int it = 0; it < TN / 32; ++it) {
    int c = it * 256 + tid;
    int row = c >> 3, pc = c & 7;
    int gc = pc ^ (row & 7);
    async_cp16(B + (size_t)row * K + (k0 + gc * 8),
               &L[TM * 64 + (it * 256 + wave * 64) * 8]);
  }
}

__device__ __forceinline__ void compute_tile(
    const u16* L, int lane, int wrow, int wcol, f32x16 (&acc)[2][2]) {
  constexpr int TM = 128;
  #pragma unroll
  for (int s = 0; s < 4; ++s) {        // 4 k-steps of K=16
    const int h = s * 2 + (lane >> 5); // 16B chunk along K this lane needs
    bf16x8 bfr[2], afr[2];
    #pragma unroll
    for (int j = 0; j < 2; ++j) {
      const int rb = wcol * 64 + j * 32 + (lane & 31);
      bfr[j] = *(const bf16x8*)&L[TM * 64 + (rb * 8 + (h ^ (rb & 7))) * 8];
    }
    #pragma unroll
    for (int i = 0; i < 2; ++i) {
      const int ra = wrow * 64 + i * 32 + (lane & 31);
      afr[i] = *(const bf16x8*)&L[(ra * 8 + (h ^ (ra & 7))) * 8];
    }
    #pragma unroll
    for (int i = 0; i < 2; ++i)
      #pragma unroll
      for (int j = 0; j < 2; ++j)
        acc[i][j] = __builtin_amdgcn_mfma_f32_32x32x16_bf16(
            afr[i], bfr[j], acc[i][j], 0, 0, 0);
  }
}

__device__ __forceinline__ void mainloop(
    const u16* __restrict__ A, const u16* __restrict__ B, int K,
    int kbeg, int kend, int tid, u16* lds, f32x16 (&acc)[2][2]) {
  constexpr int BK = 64;
  constexpr int BUF = 16384;           // u16 per LDS buffer (32 KiB)
  const int lane = tid & 63;
  const int wave = tid >> 6;
  const int wrow = wave >> 1, wcol = wave & 1;

  stage_tile(A, B, K, kbeg, tid, lds); // prologue: tile 0 -> buf 0
  int cur = 0;
  for (int k0 = kbeg; k0 < kend; k0 += BK) {
    if (k0 + BK < kend) {
      stage_tile(A, B, K, k0 + BK, tid, lds + (cur ^ 1) * BUF);
      asm volatile("s_waitcnt vmcnt(8)" ::: "memory");
    } else {
      asm volatile("s_waitcnt vmcnt(0)" ::: "memory");
    }
    __builtin_amdgcn_s_barrier();      // all waves: current buffer complete
    compute_tile(lds + cur * BUF, lane, wrow, wcol, acc);
    __builtin_amdgcn_s_barrier();      // all waves done reading before next
    cur ^= 1;                          // iter overwrites this buffer
  }
}

// ============== 256^2 deep-pipeline ring mainloop (gemm3, R19) ==============
// Ring of 4 buffers x BK=32 (32 KiB each = A 16KB + B 16KB). Prefetch depth 3.
// Per tile 2 phases (s=0,1); per phase: 6 ds_read_b128 + stage 1 unit (2
// global_load_lds) -> barrier -> lgkmcnt(0) -> sched_barrier -> setprio(1) ->
// 8 MFMA -> setprio(0) -> [vmcnt at s==1] -> barrier. vmcnt(8) steady state
// (t+2,t+3 in flight), epilogue 4 -> 0. Swizzle: gc = pc ^ ((row>>1)&3)
// spreads 32 rows uniformly over all 8 bank-groups (4 lanes/group = floor).
// 8 waves in 2x4 grid: wave covers 128x64 = 4x2 acc tiles of 32x32.

__device__ __forceinline__ void stage_unit32(
    const u16* __restrict__ M, int K, int k0, int tid, u16* Lbase) {
  #pragma unroll
  for (int it = 0; it < 2; ++it) {     // 256 rows x 4 chunks = 1024 = 2 x 512
    int c = it * 512 + tid;            // chunk index = LDS slot (linear dest)
    int row = c >> 2, pc = c & 3;
    int gc = pc ^ ((row >> 1) & 3);    // pre-swizzled SOURCE (rule #21)
    async_cp16(M + (size_t)row * K + (k0 + gc * 8),
               &Lbase[(it * 512 + (tid >> 6) * 64) * 8]);
  }
}

__device__ __forceinline__ void mainloop32(
    const u16* __restrict__ A, const u16* __restrict__ B, int K,
    int kbeg, int tid, u16* lds, f32x16 (&acc)[4][2]) {
  constexpr int NT = 16;               // 512 K-span / BK=32
  constexpr int BUFS = 16384;          // u16 per ring buffer (32 KiB)
  const int lane = tid & 63;
  const int wave = tid >> 6;
  const int wrow = wave >> 2, wcol = wave & 3;

  // prologue: stage tiles 0,1,2 (12 instr/thread in flight)
  #pragma unroll
  for (int p = 0; p < 3; ++p) {
    stage_unit32(A, K, kbeg + p * 32, tid, lds + p * BUFS);
    stage_unit32(B, K, kbeg + p * 32, tid, lds + p * BUFS + 8192);
  }
  asm volatile("s_waitcnt vmcnt(8)" ::: "memory");  // tile 0 complete
  __builtin_amdgcn_s_barrier();

  for (int t = 0; t < NT; ++t) {
    const u16* L = lds + (t & 3) * BUFS;
    u16* Lnxt = lds + ((t + 3) & 3) * BUFS;
    const int k3 = kbeg + (t + 3) * 32;
    #pragma unroll
    for (int s = 0; s < 2; ++s) {
      const int h = s * 2 + (lane >> 5);   // 16B chunk along K (0..3)
      bf16x8 bfr[2], afr[4];
      #pragma unroll
      for (int j = 0; j < 2; ++j) {
        const int rb = wcol * 64 + j * 32 + (lane & 31);
        bfr[j] = *(const bf16x8*)&L[8192 + (rb * 4 + (h ^ ((rb >> 1) & 3))) * 8];
      }
      #pragma unroll
      for (int i = 0; i < 4; ++i) {
        const int ra = wrow * 128 + i * 32 + (lane & 31);
        afr[i] = *(const bf16x8*)&L[(ra * 4 + (h ^ ((ra >> 1) & 3))) * 8];
      }
      if (t < NT - 3) {                    // stage tile t+3 (ring[(t+3)&3])
        if (s == 0) stage_unit32(A, K, k3, tid, Lnxt);
        else        stage_unit32(B, K, k3, tid, Lnxt + 8192);
      }
      __builtin_amdgcn_s_barrier();
      asm volatile("s_waitcnt lgkmcnt(0)" ::: "memory");
      __builtin_amdgcn_sched_barrier(0);   // rule #18: pin MFMA after the wait
      __builtin_amdgcn_s_setprio(1);
      #pragma unroll
      for (int i = 0; i < 4; ++i)
        #pragma unroll
        for (int j = 0; j < 2; ++j)
          acc[i][j] = __builtin_amdgcn_mfma_f32_32x32x16_bf16(
              afr[i], bfr[j], acc[i][j], 0, 0, 0);
      __builtin_amdgcn_s_setprio(0);
      if (s == 1) {                        // once per tile: gate tile t+1
        if (t < NT - 3)       asm volatile("s_waitcnt vmcnt(8)" ::: "memory");
        else if (t == NT - 3) asm volatile("s_waitcnt vmcnt(4)" ::: "memory");
        else if (t == NT - 2) asm volatile("s_waitcnt vmcnt(0)" ::: "memory");
      }
      __builtin_amdgcn_s_barrier();
    }
  }
}

// 32x32 C/D mapping (m74/m101 verified): col = lane&31,
// row = (reg&3) + 8*(reg>>2) + 4*(lane>>5), reg in [0,16).

// ---- GEMM1+GEMM2 merged: [x; proto](4608 x 1024) @ feat^T, tile 128x128 ----
// 1D grid 576; XCD-supertile decode (9x8 panel per XCD). UNCHANGED from R16.
__global__ __launch_bounds__(256) void gemm12(
    const u16* __restrict__ xb, const u16* __restrict__ pb,
    const u16* __restrict__ fb, u16* __restrict__ Acat, u16* __restrict__ Bcat,
    const float* __restrict__ alpha, const float* __restrict__ beta,
    const float* __restrict__ theta) {
  constexpr int TM = 128, K = 1024, N = 2048;
  constexpr int TSTRIDE = 136;           // u16; 272B rows = 17*16B aligned
  __shared__ u16 lds[32768];             // 64 KiB: 2 mainloop bufs; transpose reuses

  const int tid = threadIdx.x;
  const int lane = tid & 63;
  const int wave = tid >> 6;
  const int wrow = wave >> 1, wcol = wave & 1;

  // XCD-aware supertile decode (bijective: 576 = 8 * 72, panels 9x8)
  const int bid = blockIdx.x;
  const int xcd = bid & 7, slot = bid >> 3;        // xcd 0..7, slot 0..71
  const int xt = (xcd & 3) * 9 + (slot >> 3);      // 0..35
  const int yt = (xcd >> 2) * 8 + (slot & 7);      // 0..15

  const int bm_all = xt * TM;
  const int bn = yt * 128;
  const bool is_x = bm_all < 4096;       // block purely x or proto (4096%128==0)
  const u16* A = is_x ? xb + (size_t)bm_all * K : pb + (size_t)(bm_all - 4096) * K;
  const u16* B = fb + (size_t)bn * K;

  f32x16 acc[2][2] = {};
  mainloop(A, B, K, 0, K, tid, lds, acc);

  float th = 0.f, al = 0.f, be = 0.f;
  if (!is_x) { th = theta[0]; al = alpha[0]; be = beta[0]; }
  u16* dst = is_x ? Acat : Bcat;
  const int rowbase = is_x ? bm_all : bm_all - 4096;
  const int rquad = 4 * (lane >> 5);

  #pragma unroll
  for (int half = 0; half < 2; ++half) {
    __syncthreads();   // protect lds reuse (mainloop end / previous half's reads)
    #pragma unroll
    for (int i = 0; i < 2; ++i) {
      #pragma unroll
      for (int j = 0; j < 2; ++j) {
        const int cl = wcol * 64 + j * 32 + (lane & 31);
        #pragma unroll
        for (int r = 0; r < 16; ++r) {
          const int rl = wrow * 64 + i * 32 + (r & 3) + 8 * (r >> 2) + rquad;
          float v = acc[i][j][r];
          float pres = v > 0.f ? v : 0.f;
          float o;
          if (is_x) o = half == 0 ? v * pres : 1.f - pres;
          else {
            float cc = v * pres;
            o = half == 0 ? th * cc - al * (1.f - pres) : -be * cc;
          }
          lds[rl * TSTRIDE + cl] = f2bf(o);
        }
      }
    }
    __syncthreads();
    #pragma unroll
    for (int v = 0; v < 8; ++v) {
      const int rl = v * 16 + (tid >> 4);
      const int c8 = (tid & 15) * 8;
      u16x8 vec = *(const u16x8*)&lds[rl * TSTRIDE + c8];
      *(u16x8*)&dst[(size_t)(rowbase + rl) * (2 * N) + bn + c8 + half * N] = vec;
    }
  }
}

// ---- GEMM3 split-K: part[z] = Acat @ Bcat^T partial (bf16), tile 256x256 ----
// KSPLIT=8, 1D grid 256 = 1 block/CU, 512 thr, deep-pipeline ring mainloop.
// z-slice = XCD (bid%8); slot = bid/8: bxt = slot%16, byt = slot/16.
// Partials bf16 thread-linear: tile = 65536 u16; chunk q = i*4+j*2+h (0..15).
__global__ __launch_bounds__(512) void gemm3(
    const u16* __restrict__ Acat, const u16* __restrict__ Bcat,
    u16* __restrict__ part) {
  constexpr int K = 4096, KSPLIT = 8;
  __shared__ u16 lds[65536];             // 128 KiB: ring of 4 x 32 KiB

  const int tid = threadIdx.x;
  const int bid = blockIdx.x;
  const int bz = bid & 7;                          // z-slice = XCD
  const int slot = bid >> 3;                       // 0..31
  const int bxt = slot & 15;                       // 0..15
  const int byt = slot >> 4;                       // 0..1

  const int bm = bxt * 256;
  const int bn = byt * 256;
  const int kbeg = bz * (K / KSPLIT);

  f32x16 acc[4][2] = {};
  mainloop32(Acat + (size_t)bm * K, Bcat + (size_t)bn * K, K, kbeg,
             tid, lds, acc);

  const int tileId = byt * 16 + bxt;               // 0..31
  const size_t pbase = ((size_t)bz * 32 + tileId) * 65536;
  #pragma unroll
  for (int i = 0; i < 4; ++i)
    #pragma unroll
    for (int j = 0; j < 2; ++j)
      #pragma unroll
      for (int h = 0; h < 2; ++h) {
        u16x8 o;
        #pragma unroll
        for (int e = 0; e < 8; ++e) o[e] = f2bf(acc[i][j][h * 8 + e]);
        *(u16x8*)&part[pbase + (size_t)(i * 4 + j * 2 + h) * 4096 + tid * 8] = o;
      }
}

// ---- reduce bf16 partials over z=0..8, scatter fp32 to out ----
// 512 blocks x 512 thr: one q-chunk per block (tileId = bid>>4, q = bid&15).
// Mirrors gemm3 256^2 map: q = i*4+j*2+h; reg = h*8+e; wave 2x4 grid:
// row = bm + (wave>>2)*128 + i*32 + (reg&3)+8*(reg>>2)+4*(lane>>5);
// col = bn + (wave&3)*64 + j*32 + (lane&31).
__global__ __launch_bounds__(512) void reduce4(
    const u16* __restrict__ part, float* __restrict__ out) {
  constexpr int N = 512;
  const int tid = threadIdx.x;
  const int lane = tid & 63;
  const int wave = tid >> 6;
  const int wrow = wave >> 2, wcol = wave & 3;
  const int tileId = blockIdx.x >> 4;      // 0..31 = byt*16+bxt
  const int q = blockIdx.x & 15;
  const int bm = (tileId & 15) * 256;
  const int bn = (tileId >> 4) * 256;

  float v[8] = {};
  #pragma unroll
  for (int z = 0; z < 8; ++z) {
    u16x8 u = *(const u16x8*)&part[((size_t)z * 32 + tileId) * 65536 +
                                   (size_t)q * 4096 + tid * 8];
    #pragma unroll
    for (int e = 0; e < 8; ++e) v[e] += bf2f(u[e]);
  }
  const int i = q >> 2, j = (q >> 1) & 1, h = q & 1;
  const int gc = bn + wcol * 64 + j * 32 + (lane & 31);
  const int grb = bm + wrow * 128 + i * 32 + 4 * (lane >> 5);
  #pragma unroll
  for (int e = 0; e < 8; ++e) {
    const int reg = h * 8 + e;
    out[(size_t)(grb + (reg & 3) + 8 * (reg >> 2)) * N + gc] = v[e];
  }
}

extern "C" void kernel_launch(void* const* d_in, const int* in_sizes, int n_in,
                              void* d_out, int out_size, void* d_ws, size_t ws_size,
                              hipStream_t stream) {
  const float* x     = (const float*)d_in[0];
  const float* feat  = (const float*)d_in[1];
  const float* proto = (const float*)d_in[2];
  const float* alpha = (const float*)d_in[3];
  const float* beta  = (const float*)d_in[4];
  const float* theta = (const float*)d_in[5];
  float* out = (float*)d_out;

  constexpr int Bb = 4096, Ii = 1024, Pp = 512, Ff = 2048;

  // ws layout (NO aliasing — R12 defensive change): casts | Acat | Bcat | part.
  // Total ~105 MB of the 256 MiB workspace.
  char* ws = (char*)d_ws;
  u16* xb   = (u16*)ws;                               // 8.4 MB
  u16* fb   = xb + (size_t)Bb * Ii;                   // 4.2 MB
  u16* pb   = fb + (size_t)Ff * Ii;                   // 1.0 MB
  size_t r0 = 33554432;                               // 32 MiB region0 (casts)
  u16* Acat = (u16*)(ws + r0);                        // 33.6 MB
  u16* Bcat = Acat + (size_t)Bb * 2 * Ff;             // 4.2 MB
  u16* part = Bcat + (size_t)Pp * 2 * Ff;             // 33.6 MB (KSPLIT=8)

  const int n1 = Bb * Ii, n2 = Ff * Ii, n3 = Pp * Ii;
  cast3<<<((n1 + n2 + n3) / 8 + 255) / 256, 256, 0, stream>>>(
      x, feat, proto, xb, n1, n2, n3);

  // merged GEMM1+GEMM2: M=4608, N=2048; 1D grid 576 with XCD supertile decode
  gemm12<<<576, 256, 0, stream>>>(xb, pb, fb, Acat, Bcat, alpha, beta, theta);

  // GEMM3: 4096x512, K=4096 split 8 ways; 256^2 tile, ring pipeline, grid 256
  gemm3<<<256, 512, 0, stream>>>(Acat, Bcat, part);

  // reduce z=0..8 -> out (16 chunks per tile, one per block)
  reduce4<<<512, 512, 0, stream>>>(part, out);
}